// Round 3
// baseline (114.437 us; speedup 1.0000x reference)
//
#include <hip/hip_runtime.h>
#include <math.h>

#define POS_WEIGHT 7.0f
#define POSITION_WEIGHT 0.1f
#define BLOCK 256
#define EPT 32          // elements per thread (contiguous run)

// p = sigmoid(d), using precomputed e = exp(-|d|), rt = 1/(1+e)
__device__ __forceinline__ float sigmoid_from(float d, float e, float rt) {
    return (d >= 0.0f ? 1.0f : e) * rt;
}

__global__ __launch_bounds__(BLOCK, 4) void pos_loss_kernel(
    const float* __restrict__ logits,   // [n,2]
    const int*   __restrict__ labels,   // [n]
    const int*   __restrict__ batch,    // [n]
    float4* __restrict__ partials,      // [nblocks]
    int n)
{
    const int t     = blockIdx.x * BLOCK + threadIdx.x;
    const int base0 = t * EPT;

    float s_wnll = 0.0f, s_w = 0.0f, s_pos = 0.0f;
    // running previous-element state; ba = -1 sentinel (batch ids >= 0) makes
    // the first pair-condition false without a branch
    float prev_p = 0.0f;  int prev_ba = -1, prev_la = 0;
    float first_p = 0.0f; int first_ba = -2, first_la = 0;

    const float4* lg4 = (const float4*)logits;
    const int4*   lb4 = (const int4*)labels;
    const int4*   bt4 = (const int4*)batch;

    #pragma unroll
    for (int j = 0; j < EPT / 8; ++j) {
        const int base = base0 + j * 8;
        if (base + 8 <= n) {
            // 8 rows of logits = 4x float4; labels/batch = 2x int4 each
            float4 L0 = lg4[(base >> 1) + 0];
            float4 L1 = lg4[(base >> 1) + 1];
            float4 L2 = lg4[(base >> 1) + 2];
            float4 L3 = lg4[(base >> 1) + 3];
            int4 A0 = lb4[(base >> 2) + 0];
            int4 A1 = lb4[(base >> 2) + 1];
            int4 B0 = bt4[(base >> 2) + 0];
            int4 B1 = bt4[(base >> 2) + 1];

            float d[8] = { L0.y - L0.x, L0.w - L0.z, L1.y - L1.x, L1.w - L1.z,
                           L2.y - L2.x, L2.w - L2.z, L3.y - L3.x, L3.w - L3.z };
            int la[8] = { A0.x, A0.y, A0.z, A0.w, A1.x, A1.y, A1.z, A1.w };
            int ba[8] = { B0.x, B0.y, B0.z, B0.w, B1.x, B1.y, B1.z, B1.w };

            #pragma unroll
            for (int k = 0; k < 8; ++k) {
                float dk = d[k];
                float a  = fabsf(dk);
                float e  = __expf(-a);
                float t1 = 1.0f + e;
                float Lg = __logf(t1);                 // softplus(-a)
                float rt = __builtin_amdgcn_rcpf(t1);
                bool dpos = dk >= 0.0f;
                float p  = sigmoid_from(dk, e, rt);
                bool xpos = la[k] ? !dpos : dpos;      // sign of softplus arg
                float nll = Lg + (xpos ? a : 0.0f);
                float w   = la[k] ? POS_WEIGHT : 1.0f;
                s_wnll = fmaf(w, nll, s_wnll);
                s_w   += w;
                if (j == 0 && k == 0) { first_p = p; first_ba = ba[0]; first_la = la[0]; }
                if (prev_ba == ba[k] && (prev_la | la[k]))
                    s_pos += fabsf(p - prev_p);
                prev_p = p; prev_ba = ba[k]; prev_la = la[k];
            }
        } else if (base < n) {
            // scalar tail (unused for N divisible by 8, kept for correctness)
            for (int i = base; i < n && i < base + 8; ++i) {
                float d0 = logits[2 * i + 1] - logits[2 * i];
                float a  = fabsf(d0);
                float e  = __expf(-a);
                float t1 = 1.0f + e;
                float Lg = __logf(t1);
                float rt = __builtin_amdgcn_rcpf(t1);
                bool dpos = d0 >= 0.0f;
                float p  = sigmoid_from(d0, e, rt);
                int  li  = labels[i];
                bool xpos = li ? !dpos : dpos;
                float w  = li ? POS_WEIGHT : 1.0f;
                s_wnll  += w * (Lg + (xpos ? a : 0.0f));
                s_w     += w;
                int bi = batch[i];
                if (i == base0) { first_p = p; first_ba = bi; first_la = li; }
                if (prev_ba == bi && (prev_la | li))
                    s_pos += fabsf(p - prev_p);
                prev_p = p; prev_ba = bi; prev_la = li;
            }
        }
    }

    // cross-thread boundary pair (base0-1, base0): previous thread is the
    // previous LANE (contiguous thread ranges). Lane 0 loads once per thread.
    {
        float bp  = __shfl_up(prev_p, 1);
        int   bba = __shfl_up(prev_ba, 1);
        int   bla = __shfl_up(prev_la, 1);
        if ((threadIdx.x & 63) == 0 && t > 0 && base0 < n) {
            int i = base0 - 1;
            float2 lp = ((const float2*)logits)[i];
            bla = labels[i];
            bba = batch[i];
            float dd = lp.y - lp.x;
            float aa = fabsf(dd);
            float ee = __expf(-aa);
            bp = sigmoid_from(dd, ee, __builtin_amdgcn_rcpf(1.0f + ee));
        }
        if (t > 0 && base0 < n && bba == first_ba && (bla | first_la))
            s_pos += fabsf(first_p - bp);
    }

    // wave(64) reduce
    #pragma unroll
    for (int off = 32; off > 0; off >>= 1) {
        s_wnll += __shfl_down(s_wnll, off);
        s_w    += __shfl_down(s_w, off);
        s_pos  += __shfl_down(s_pos, off);
    }

    __shared__ float sa[BLOCK / 64], sb[BLOCK / 64], sc[BLOCK / 64];
    int lane = threadIdx.x & 63;
    int wid  = threadIdx.x >> 6;
    if (lane == 0) { sa[wid] = s_wnll; sb[wid] = s_w; sc[wid] = s_pos; }
    __syncthreads();
    if (threadIdx.x == 0) {
        float ta = 0.0f, tb = 0.0f, tc = 0.0f;
        #pragma unroll
        for (int w = 0; w < BLOCK / 64; ++w) { ta += sa[w]; tb += sb[w]; tc += sc[w]; }
        partials[blockIdx.x] = make_float4(ta, tb, tc, 0.0f);
    }
}

__global__ __launch_bounds__(256) void finalize_kernel(
    const float4* __restrict__ partials, int nb, float* __restrict__ out)
{
    float a = 0.0f, b = 0.0f, c = 0.0f;
    for (int i = threadIdx.x; i < nb; i += 256) {
        float4 v = partials[i];
        a += v.x; b += v.y; c += v.z;
    }
    #pragma unroll
    for (int off = 32; off > 0; off >>= 1) {
        a += __shfl_down(a, off);
        b += __shfl_down(b, off);
        c += __shfl_down(c, off);
    }
    __shared__ float sa[4], sb[4], sc[4];
    int lane = threadIdx.x & 63;
    int wid  = threadIdx.x >> 6;
    if (lane == 0) { sa[wid] = a; sb[wid] = b; sc[wid] = c; }
    __syncthreads();
    if (threadIdx.x == 0) {
        float ta = 0.0f, tb = 0.0f, tc = 0.0f;
        #pragma unroll
        for (int w = 0; w < 4; ++w) { ta += sa[w]; tb += sb[w]; tc += sc[w]; }
        out[0] = ta / tb + POSITION_WEIGHT * tc;
    }
}

extern "C" void kernel_launch(void* const* d_in, const int* in_sizes, int n_in,
                              void* d_out, int out_size, void* d_ws, size_t ws_size,
                              hipStream_t stream) {
    const float* logits = (const float*)d_in[0];
    const int*   labels = (const int*)d_in[1];
    const int*   batch  = (const int*)d_in[2];
    float* out = (float*)d_out;
    float4* partials = (float4*)d_ws;
    int n = in_sizes[1];   // labels element count == N

    int nblocks = (n + EPT * BLOCK - 1) / (EPT * BLOCK);   // 2048 for N=16M
    pos_loss_kernel<<<nblocks, BLOCK, 0, stream>>>(logits, labels, batch, partials, n);
    finalize_kernel<<<1, 256, 0, stream>>>(partials, nblocks, out);
}

// Round 4
// 48.142 us; speedup vs baseline: 2.3771x; 2.3771x over previous
//
#include <hip/hip_runtime.h>
#include <math.h>

#define POS_WEIGHT 7.0f
#define POSITION_WEIGHT 0.1f
#define BLOCK 256
#define STEP 2048              // rows per block-step (256 threads x 8 rows)
#define STEPS 4                // steps per block
#define RPB (STEP * STEPS)     // rows per block = 8192

// p = sigmoid(d), stable, fast hw ops only
__device__ __forceinline__ float sigp(float d) {
    float e  = __expf(-fabsf(d));
    float rt = __builtin_amdgcn_rcpf(1.0f + e);
    return (d >= 0.0f ? 1.0f : e) * rt;
}

// weighted NLL from p: nll = -log(label ? p : 1-p), w = label ? 7 : 1
__device__ __forceinline__ void acc_nll(int la, float p, float& s_wnll, float& s_w) {
    float sel = la ? p : 1.0f - p;
    float w   = la ? POS_WEIGHT : 1.0f;
    s_wnll = fmaf(w, -__logf(sel), s_wnll);
    s_w += w;
}

__device__ __forceinline__ void pair_term(int la0, int ba0, float p0,
                                          int la1, int ba1, float p1, float& s_pos) {
    if (ba0 == ba1 && (la0 | la1)) s_pos += fabsf(p1 - p0);
}

__global__ __launch_bounds__(BLOCK, 4) void pos_loss_kernel(
    const float* __restrict__ logits,   // [n,2]
    const int*   __restrict__ labels,   // [n]
    const int*   __restrict__ batch,    // [n]
    float4* __restrict__ partials,      // [nblocks]
    int n)
{
    __shared__ __align__(16) float Pf[STEP + 8];   // p per row of this step (+pad)
    __shared__ int   Mb[2 * BLOCK];                // first-meta of each thread's groups
    __shared__ float prevP;                        // carry across steps/blocks
    __shared__ int   prevM;

    const int t  = threadIdx.x;
    const long long bb = (long long)blockIdx.x * RPB;

    float s_wnll = 0.f, s_w = 0.f, s_pos = 0.f;
    float carry_p = 0.f; int carry_m = -2;         // ba = -1 sentinel, never matches

    // block-boundary predecessor (row bb-1), once per block, one thread
    if (t == BLOCK - 1 && bb > 0 && bb < n) {
        int i = (int)bb - 1;
        float2 lp = ((const float2*)logits)[i];
        carry_p = sigp(lp.y - lp.x);
        carry_m = (batch[i] << 1) | labels[i];
    }

    for (int s = 0; s < STEPS; ++s) {
        const long long row0l = bb + (long long)s * STEP;
        if (row0l >= n) break;
        const int row0 = (int)row0l;

        if (row0 + STEP <= n) {
            // ---------- fast full step: all loads lane-stride-16B ----------
            const float4* lg4 = (const float4*)logits + (row0 >> 1);
            const int4*   lb4 = (const int4*)labels + (row0 >> 2);
            const int4*   bt4 = (const int4*)batch  + (row0 >> 2);

            float4 L0 = lg4[t];           // rows 2t, 2t+1
            float4 L1 = lg4[256 + t];     // rows 512+2t, +1
            float4 L2 = lg4[512 + t];     // rows 1024+2t, +1
            float4 L3 = lg4[768 + t];     // rows 1536+2t, +1
            int4 laA = lb4[t];            // rows 4t..4t+3
            int4 laB = lb4[256 + t];      // rows 1024+4t..+3
            int4 baA = bt4[t];
            int4 baB = bt4[256 + t];

            if (t == BLOCK - 1) { prevP = carry_p; prevM = carry_m; }

            // phase A: p in the coalesced domain -> LDS (label-free)
            float2* P2 = (float2*)Pf;
            P2[t]       = make_float2(sigp(L0.y - L0.x), sigp(L0.w - L0.z));
            P2[256 + t] = make_float2(sigp(L1.y - L1.x), sigp(L1.w - L1.z));
            P2[512 + t] = make_float2(sigp(L2.y - L2.x), sigp(L2.w - L2.z));
            P2[768 + t] = make_float2(sigp(L3.y - L3.x), sigp(L3.w - L3.z));
            Mb[t]         = (baA.x << 1) | laA.x;
            Mb[BLOCK + t] = (baB.x << 1) | laB.x;
            __syncthreads();

            // phase B: row-aligned consumption (4 contiguous rows x 2 groups)
            float4 pA = ((const float4*)Pf)[t];          // rows 4t..4t+3
            float4 pB = ((const float4*)Pf)[256 + t];    // rows 1024+4t..+3
            float pA4 = Pf[4 * t + 4];                   // row 4t+4 (t=255 -> row 1024, valid)
            float pB4 = Pf[1024 + 4 * t + 4];            // row 1024+4t+4 (t=255 -> pad, guarded)

            acc_nll(laA.x, pA.x, s_wnll, s_w);
            acc_nll(laA.y, pA.y, s_wnll, s_w);
            acc_nll(laA.z, pA.z, s_wnll, s_w);
            acc_nll(laA.w, pA.w, s_wnll, s_w);
            acc_nll(laB.x, pB.x, s_wnll, s_w);
            acc_nll(laB.y, pB.y, s_wnll, s_w);
            acc_nll(laB.z, pB.z, s_wnll, s_w);
            acc_nll(laB.w, pB.w, s_wnll, s_w);

            pair_term(laA.x, baA.x, pA.x, laA.y, baA.y, pA.y, s_pos);
            pair_term(laA.y, baA.y, pA.y, laA.z, baA.z, pA.z, s_pos);
            pair_term(laA.z, baA.z, pA.z, laA.w, baA.w, pA.w, s_pos);
            { int m = Mb[t + 1]; pair_term(laA.w, baA.w, pA.w, m & 1, m >> 1, pA4, s_pos); }
            pair_term(laB.x, baB.x, pB.x, laB.y, baB.y, pB.y, s_pos);
            pair_term(laB.y, baB.y, pB.y, laB.z, baB.z, pB.z, s_pos);
            pair_term(laB.z, baB.z, pB.z, laB.w, baB.w, pB.w, s_pos);
            if (t < BLOCK - 1) {
                int m = Mb[BLOCK + t + 1];
                pair_term(laB.w, baB.w, pB.w, m & 1, m >> 1, pB4, s_pos);
            }
            if (t == 0)
                pair_term(prevM & 1, prevM >> 1, prevP, laA.x, baA.x, pA.x, s_pos);
            if (t == BLOCK - 1) { carry_p = pB.w; carry_m = (baB.w << 1) | laB.w; }
            __syncthreads();
        } else {
            // ---------- masked tail step (never hit for N=16M) ----------
            if (t == BLOCK - 1) { prevP = carry_p; prevM = carry_m; }
            __syncthreads();
            for (int g = 0; g < 2; ++g) {
                int rb = row0 + g * 1024 + 4 * t;
                #pragma unroll
                for (int k = 0; k < 4; ++k) {
                    int r = rb + k;
                    if (r < n) {
                        float2 lp = ((const float2*)logits)[r];
                        int la = labels[r], ba = batch[r];
                        float p = sigp(lp.y - lp.x);
                        acc_nll(la, p, s_wnll, s_w);
                        if (r + 1 < n) {
                            float2 lq = ((const float2*)logits)[r + 1];
                            pair_term(la, ba, p, labels[r + 1], batch[r + 1],
                                      sigp(lq.y - lq.x), s_pos);
                        }
                    }
                }
            }
            if (t == 0) {
                float2 lp = ((const float2*)logits)[row0];
                pair_term(prevM & 1, prevM >> 1, prevP,
                          labels[row0], batch[row0], sigp(lp.y - lp.x), s_pos);
            }
            __syncthreads();
        }
    }

    // wave(64) reduce -> block partial
    #pragma unroll
    for (int off = 32; off > 0; off >>= 1) {
        s_wnll += __shfl_down(s_wnll, off);
        s_w    += __shfl_down(s_w, off);
        s_pos  += __shfl_down(s_pos, off);
    }
    __shared__ float sa[BLOCK / 64], sb[BLOCK / 64], sc[BLOCK / 64];
    int lane = t & 63, wid = t >> 6;
    if (lane == 0) { sa[wid] = s_wnll; sb[wid] = s_w; sc[wid] = s_pos; }
    __syncthreads();
    if (t == 0) {
        float ta = 0.f, tb = 0.f, tc = 0.f;
        #pragma unroll
        for (int w = 0; w < BLOCK / 64; ++w) { ta += sa[w]; tb += sb[w]; tc += sc[w]; }
        partials[blockIdx.x] = make_float4(ta, tb, tc, 0.f);
    }
}

__global__ __launch_bounds__(256) void finalize_kernel(
    const float4* __restrict__ partials, int nb, float* __restrict__ out)
{
    float a = 0.f, b = 0.f, c = 0.f;
    for (int i = threadIdx.x; i < nb; i += 256) {
        float4 v = partials[i];
        a += v.x; b += v.y; c += v.z;
    }
    #pragma unroll
    for (int off = 32; off > 0; off >>= 1) {
        a += __shfl_down(a, off);
        b += __shfl_down(b, off);
        c += __shfl_down(c, off);
    }
    __shared__ float sa[4], sb[4], sc[4];
    int lane = threadIdx.x & 63, wid = threadIdx.x >> 6;
    if (lane == 0) { sa[wid] = a; sb[wid] = b; sc[wid] = c; }
    __syncthreads();
    if (threadIdx.x == 0) {
        float ta = 0.f, tb = 0.f, tc = 0.f;
        #pragma unroll
        for (int w = 0; w < 4; ++w) { ta += sa[w]; tb += sb[w]; tc += sc[w]; }
        out[0] = ta / tb + POSITION_WEIGHT * tc;
    }
}

extern "C" void kernel_launch(void* const* d_in, const int* in_sizes, int n_in,
                              void* d_out, int out_size, void* d_ws, size_t ws_size,
                              hipStream_t stream) {
    const float* logits = (const float*)d_in[0];
    const int*   labels = (const int*)d_in[1];
    const int*   batch  = (const int*)d_in[2];
    float* out = (float*)d_out;
    float4* partials = (float4*)d_ws;
    int n = in_sizes[1];   // labels element count == N

    int nblocks = (n + RPB - 1) / RPB;   // 2048 for N=16M
    pos_loss_kernel<<<nblocks, BLOCK, 0, stream>>>(logits, labels, batch, partials, n);
    finalize_kernel<<<1, 256, 0, stream>>>(partials, nblocks, out);
}